// Round 6
// baseline (240.883 us; speedup 1.0000x reference)
//
#include <hip/hip_runtime.h>

#define Bn 8
#define Nn 4096
#define Pn 4096
#define Kn 32
#define Cn 128

using float4v = __attribute__((ext_vector_type(4))) float;
using short8  = __attribute__((ext_vector_type(8))) short;

__device__ __forceinline__ unsigned short bf16b(float f) {
  union { float f; unsigned u; } v; v.f = f;
  unsigned r = v.u + 0x7FFFu + ((v.u >> 16) & 1u);   // round-nearest-even
  return (unsigned short)(r >> 16);
}

// (hi16(x)) | (hi16(y)<<16) — truncating f32->bf16 pair pack, one v_perm_b32
__device__ __forceinline__ unsigned pkhi(float x, float y) {
  return __builtin_amdgcn_perm(__float_as_uint(y), __float_as_uint(x), 0x07060302u);
}

// ---------------------------------------------------------------------------
// prep: blocks 0-63: WlT[n][k] = bf16(Wl[k][n]); blocks 64-95: xyz copy into
// d_out (+ block 64 zeroes gacc).
// ---------------------------------------------------------------------------
__global__ __launch_bounds__(256) void prep(const float* __restrict__ Wl,
                                            unsigned short* __restrict__ WlT,
                                            const float* __restrict__ xyz,
                                            float* __restrict__ out,
                                            float* __restrict__ gacc) {
  __shared__ unsigned short tile[128 * 33];   // [n][kl], +1 pad
  const int t = threadIdx.x, blk = blockIdx.x;
  if (blk < 64) {
#pragma unroll
    for (int i = 0; i < 16; ++i) {
      int idx = i * 256 + t;                  // 0..4095
      int kl = idx >> 7, n = idx & 127;
      tile[n * 33 + kl] = bf16b(Wl[(size_t)(blk * 32 + kl) * 128 + n]);
    }
    __syncthreads();
#pragma unroll
    for (int i = 0; i < 16; ++i) {
      int idx = i * 256 + t;
      int n = idx >> 5, kl = idx & 31;
      WlT[(size_t)n * 2048 + blk * 32 + kl] = tile[n * 33 + kl];
    }
  } else {
    if (blk == 64) gacc[t] = 0.f;
    const int i0 = (blk - 64) * 3072 + t * 12;   // 32 blocks x 3072 f32
#pragma unroll
    for (int i = 0; i < 3; ++i)
      *(float4v*)(out + i0 + i * 4) = *(const float4v*)(xyz + i0 + i * 4);
  }
}

// ---------------------------------------------------------------------------
// fused v4: 2048 blocks x 4 waves x 16 points. Demand-sized for ~64 VGPRs
// (no spill): per wave 4 points (af[4]=16) + 32-ch n-slice with ONE A-row
// tile (acc[2]=8). Double-buffered Mlds (2x8KB), ONE barrier per ct: each
// region = {issue ct+1 gathers -> phase-A MFMAs on buf[cur] (covers gather
// latency) -> FIN into buf[nxt]}. Memory patterns + numerics identical to
// the round-2-verified formulas.
// ---------------------------------------------------------------------------
__global__ __launch_bounds__(256, 4) void fused(
    const float* __restrict__ points, const float* __restrict__ lc,
    const int* __restrict__ nl, const int* __restrict__ didx,
    const float* __restrict__ Ww, const float* __restrict__ bwv,
    const unsigned short* __restrict__ WlT, const float* __restrict__ blv,
    float* __restrict__ xout, float* __restrict__ gacc) {
  __shared__ unsigned short Mlds[2][16 * 256];   // 2 x 8 KB, row-XOR-swizzled
  __shared__ int nlds[16 * 32];                  // 2 KB, pre-shifted offsets
  __shared__ float red[256];

  const int t = threadIdx.x, lane = t & 63, w = t >> 6;   // w = 0..3
  const int l15 = lane & 15, q = lane >> 4;
  const int b = blockIdx.x & 7;               // XCD-affine batch
  const int pg = blockIdx.x >> 3;             // 0..255
  const int p0 = pg * 16;
  const int db = didx[b];
  const char* __restrict__ pbase = (const char*)(points + (size_t)db * Nn * Cn);

  // stage neighbor ids, pre-shifted to byte row offsets (row stride 512 B)
  {
    int2 nv = *(const int2*)(nl + (size_t)(db * Pn + p0) * Kn + t * 2);
    nv.x <<= 9; nv.y <<= 9;
    *(int2*)&nlds[t * 2] = nv;
  }

  const float Ww0 = Ww[l15], Ww1 = Ww[16 + l15], Ww2 = Ww[32 + l15];
  const float bw0 = bwv[l15];

  // weight A-frags for my 4 points: A[m=w_out=l15][k=q*8+j]
  short8 af[4];
#pragma unroll
  for (int i = 0; i < 4; ++i) {
    const int p = p0 + w * 4 + i;
    const int pk = (db * Pn + p) * Kn;
    const float* __restrict__ lcp = lc + (size_t)(pk + q * 8) * 3;
    float la[24];
#pragma unroll
    for (int v = 0; v < 6; ++v) *(float4v*)&la[v * 4] = *(const float4v*)(lcp + v * 4);
#pragma unroll
    for (int j = 0; j < 8; ++j) {
      float ww = bw0 + la[3 * j] * Ww0 + la[3 * j + 1] * Ww1 + la[3 * j + 2] * Ww2;
      af[i][j] = (short)bf16b(ww);
    }
  }

  float4v acc[2];
  acc[0] = (float4v){0.f, 0.f, 0.f, 0.f};
  acc[1] = (float4v){0.f, 0.f, 0.f, 0.f};

  __syncthreads();   // nlds ready

  // my n-slice: channels w*32 .. w*32+31 (two 16-ch tiles)
  const unsigned short* __restrict__ bp =
      WlT + (size_t)(w * 32 + l15) * 2048 + q * 8;
  const unsigned cvoff = (unsigned)(l15 * 4);

// issue 8 gathers for point (i), chunk (ct) into fdst[8]
#define ISSUE(i, ct, fdst)                                                 \
  {                                                                        \
    const int pi_ = w * 4 + (i);                                           \
    int nk_[8];                                                            \
    *(int4*)&nk_[0] = *(const int4*)&nlds[pi_ * 32 + q * 8];               \
    *(int4*)&nk_[4] = *(const int4*)&nlds[pi_ * 32 + q * 8 + 4];           \
    _Pragma("unroll") for (int j = 0; j < 8; ++j)                          \
        fdst[j] = *(const float*)(pbase + ((unsigned)nk_[j] + cvoff +      \
                                           (unsigned)((ct) * 64)));        \
  }

// pack + step1 MFMA + swizzled ds_write for point (i) into buffer (bsel)
#define FIN(i, bsel, fsrc)                                                 \
  {                                                                        \
    const int pi_ = w * 4 + (i);                                           \
    union { short8 s; unsigned u[4]; } bv_;                                \
    bv_.u[0] = pkhi(fsrc[0], fsrc[1]);                                     \
    bv_.u[1] = pkhi(fsrc[2], fsrc[3]);                                     \
    bv_.u[2] = pkhi(fsrc[4], fsrc[5]);                                     \
    bv_.u[3] = pkhi(fsrc[6], fsrc[7]);                                     \
    float4v d_ = {0.f, 0.f, 0.f, 0.f};                                     \
    d_ = __builtin_amdgcn_mfma_f32_16x16x32_bf16(af[i], bv_.s, d_, 0, 0, 0); \
    const unsigned off_ = (unsigned)((bsel) * 8192 + pi_ * 512 +           \
        ((l15 * 32 + q * 8) ^ ((pi_ & 7) << 4)));                          \
    uint2 u_;                                                              \
    u_.x = pkhi(d_[0], d_[1]);                                             \
    u_.y = pkhi(d_[2], d_[3]);                                             \
    *(uint2*)((char*)Mlds + off_) = u_;                                    \
  }

  float r0[8], r1[8];   // 2-point lookahead ring (16 VGPRs, static)

  // prologue: M(ct=0) into buffer 0
  ISSUE(0, 0, r0)
  ISSUE(1, 0, r1)
  FIN(0, 0, r0) ISSUE(2, 0, r0)
  FIN(1, 0, r1) ISSUE(3, 0, r1)
  FIN(2, 0, r0)
  FIN(3, 0, r1)
  __syncthreads();

#pragma unroll
  for (int ct = 0; ct < 8; ++ct) {
    const int cur = ct & 1, nxt = cur ^ 1;
    // issue next chunk's first gathers (longest latency first)
    if (ct < 7) {
      ISSUE(0, ct + 1, r0)
      ISSUE(1, ct + 1, r1)
    }
    // phase A: Y += M(ct) @ WlT-chunk, reads buf[cur] (covers gathers)
    const char* mb = (const char*)Mlds + cur * 8192;
    __builtin_amdgcn_s_setprio(1);
#pragma unroll
    for (int ks = 0; ks < 8; ++ks) {
      const unsigned ax = (unsigned)((ks * 64 + q * 16) ^ ((l15 & 7) << 4));
      short8 a  = *(const short8*)(mb + l15 * 512 + ax);
      short8 b0 = *(const short8*)(bp + ct * 256 + ks * 32);
      short8 b1 = *(const short8*)(bp + 32768 + ct * 256 + ks * 32);
      acc[0] = __builtin_amdgcn_mfma_f32_16x16x32_bf16(a, b0, acc[0], 0, 0, 0);
      acc[1] = __builtin_amdgcn_mfma_f32_16x16x32_bf16(a, b1, acc[1], 0, 0, 0);
    }
    __builtin_amdgcn_s_setprio(0);
    // finish next chunk's M into buf[nxt]
    if (ct < 7) {
      FIN(0, nxt, r0) ISSUE(2, ct + 1, r0)
      FIN(1, nxt, r1) ISSUE(3, ct + 1, r1)
      FIN(2, nxt, r0)
      FIN(3, nxt, r1)
    }
    __syncthreads();
  }
#undef ISSUE
#undef FIN

  // epilogue: bias, transposed store (B,C,P), disjoint per-wave channel stats
#pragma unroll
  for (int nt = 0; nt < 2; ++nt) {
    const int ch = w * 32 + nt * 16 + l15;
    const float bb = blv[ch];
    float s = 0.f, sq = 0.f;
    float4v o;
#pragma unroll
    for (int r = 0; r < 4; ++r) {
      float v = acc[nt][r] + bb; o[r] = v; s += v; sq += v * v;
    }
    *(float4v*)(xout + ((size_t)(b * Cn + ch)) * Pn + p0 + q * 4) = o;
    s += __shfl_xor(s, 16); s += __shfl_xor(s, 32);
    sq += __shfl_xor(sq, 16); sq += __shfl_xor(sq, 32);
    if (lane < 16) { red[ch] = s; red[128 + ch] = sq; }
  }
  __syncthreads();
  atomicAdd(&gacc[t], red[t]);
}

// ---------------------------------------------------------------------------
// finalize: layernorm (per-channel over B*P) + relu, in place on x chunk
// ---------------------------------------------------------------------------
__global__ __launch_bounds__(256) void finalize_ln(float* __restrict__ x,
                                                   const float* __restrict__ gacc,
                                                   const float* __restrict__ gamma,
                                                   const float* __restrict__ beta) {
  const int idx = blockIdx.x * 256 + threadIdx.x;
  const int fi = idx * 4;
  const int c = (fi >> 12) & 127;
  const float inv = 1.f / 32768.f;
  const float mean = gacc[c] * inv;
  const float var = gacc[128 + c] * inv - mean * mean;
  const float scale = rsqrtf(var + 1e-5f) * gamma[c];
  const float shift = beta[c] - mean * scale;
  float4v v = *(float4v*)(x + fi);
#pragma unroll
  for (int r = 0; r < 4; ++r) v[r] = fmaxf(v[r] * scale + shift, 0.f);
  *(float4v*)(x + fi) = v;
}

extern "C" void kernel_launch(void* const* d_in, const int* in_sizes, int n_in,
                              void* d_out, int out_size, void* d_ws, size_t ws_size,
                              hipStream_t stream) {
  const float* xyz    = (const float*)d_in[0];
  const float* points = (const float*)d_in[1];
  const float* lc     = (const float*)d_in[2];
  const int*   nl     = (const int*)d_in[3];
  const int*   didx   = (const int*)d_in[4];
  const float* Ww     = (const float*)d_in[5];
  const float* bw     = (const float*)d_in[6];
  const float* Wl     = (const float*)d_in[7];
  const float* bl     = (const float*)d_in[8];
  const float* gamma  = (const float*)d_in[9];
  const float* beta   = (const float*)d_in[10];

  float* out  = (float*)d_out;
  float* xout = out + (size_t)Bn * Pn * 3;                       // x chunk (B,C,P)
  unsigned short* WlT = (unsigned short*)d_ws;                   // 512 KB
  float* gacc = (float*)((char*)d_ws + (size_t)512 * 1024);      // 1 KB

  prep<<<96, 256, 0, stream>>>(Wl, WlT, xyz, out, gacc);
  fused<<<2048, 256, 0, stream>>>(points, lc, nl, didx, Ww, bw, WlT, bl,
                                  xout, gacc);
  finalize_ln<<<4096, 256, 0, stream>>>(xout, gacc, gamma, beta);
}

// Round 7
// 191.648 us; speedup vs baseline: 1.2569x; 1.2569x over previous
//
#include <hip/hip_runtime.h>

#define Bn 8
#define Nn 4096
#define Pn 4096
#define Kn 32
#define Cn 128

using float4v = __attribute__((ext_vector_type(4))) float;
using short8  = __attribute__((ext_vector_type(8))) short;

__device__ __forceinline__ unsigned short bf16b(float f) {
  union { float f; unsigned u; } v; v.f = f;
  unsigned r = v.u + 0x7FFFu + ((v.u >> 16) & 1u);   // round-nearest-even
  return (unsigned short)(r >> 16);
}

// (hi16(x)) | (hi16(y)<<16) — truncating f32->bf16 pair pack, one v_perm_b32
__device__ __forceinline__ unsigned pkhi(float x, float y) {
  return __builtin_amdgcn_perm(__float_as_uint(y), __float_as_uint(x), 0x07060302u);
}

// ---------------------------------------------------------------------------
// prep: blocks 0-63: WlT[n][k] = bf16(Wl[k][n]); blocks 64-95: xyz copy into
// d_out (+ block 64 zeroes gacc).
// ---------------------------------------------------------------------------
__global__ __launch_bounds__(256) void prep(const float* __restrict__ Wl,
                                            unsigned short* __restrict__ WlT,
                                            const float* __restrict__ xyz,
                                            float* __restrict__ out,
                                            float* __restrict__ gacc) {
  __shared__ unsigned short tile[128 * 33];   // [n][kl], +1 pad
  const int t = threadIdx.x, blk = blockIdx.x;
  if (blk < 64) {
#pragma unroll
    for (int i = 0; i < 16; ++i) {
      int idx = i * 256 + t;                  // 0..4095
      int kl = idx >> 7, n = idx & 127;
      tile[n * 33 + kl] = bf16b(Wl[(size_t)(blk * 32 + kl) * 128 + n]);
    }
    __syncthreads();
#pragma unroll
    for (int i = 0; i < 16; ++i) {
      int idx = i * 256 + t;
      int n = idx >> 5, kl = idx & 31;
      WlT[(size_t)n * 2048 + blk * 32 + kl] = tile[n * 33 + kl];
    }
  } else {
    if (blk == 64) gacc[t] = 0.f;
    const int i0 = (blk - 64) * 3072 + t * 12;   // 32 blocks x 3072 f32
#pragma unroll
    for (int i = 0; i < 3; ++i)
      *(float4v*)(out + i0 + i * 4) = *(const float4v*)(xyz + i0 + i * 4);
  }
}

// ---------------------------------------------------------------------------
// fused (round-4 structure, register-unlocked): 1024 blocks x 4 waves x 32
// points, single Mlds, 2 barriers per ct, 4-point gather ring.
// KEY CHANGE 1: LDS padded to ~36 KB so the allocator's LDS-occupancy bound
// (4 blocks/CU — which equals the grid-imposed residency anyway) raises the
// VGPR budget 73 -> 128; the gather ring then lives in registers and phase B
// keeps 32 loads in flight (round 4's VGPR=60 silently serialized it).
// KEY CHANGE 2: two-sided XOR swizzle  phys = row*512 + col ^
// (((row&7)^((col>>5)&7))<<4)  -> ds_write drops from 4-way to 2-way
// conflicts, ds_read stays 2-way. vmcnt-order pitfall avoided: no vmem
// prefetch across barriers (round-6 lesson).
// ---------------------------------------------------------------------------
__global__ __launch_bounds__(256, 4) void fused(
    const float* __restrict__ points, const float* __restrict__ lc,
    const int* __restrict__ nl, const int* __restrict__ didx,
    const float* __restrict__ Ww, const float* __restrict__ bwv,
    const unsigned short* __restrict__ WlT, const float* __restrict__ blv,
    float* __restrict__ xout, float* __restrict__ gacc) {
  // 32*256 used + 7424 pad -> 23.0 KB; + nlds 4 KB + red 1 KB ≈ 36.5 KB total
  __shared__ unsigned short Mlds[32 * 256 + 7424];
  __shared__ int nlds[32 * 32];               // 4 KB, pre-shifted byte offsets
  __shared__ float red[256];

  const int t = threadIdx.x, lane = t & 63, w = t >> 6;
  const int l15 = lane & 15, q = lane >> 4;
  const int b = blockIdx.x & 7;               // XCD-affine batch
  const int pg = blockIdx.x >> 3;             // 0..127
  const int p0 = pg * 32;
  const int db = didx[b];
  const char* __restrict__ pbase = (const char*)(points + (size_t)db * Nn * Cn);

  // touch the pad so it stays allocated (never true at runtime)
  if (blockIdx.x == 0xFFFFFFFFu) ((volatile unsigned short*)Mlds)[32 * 256 + t] = 0;

  // stage neighbor ids, pre-shifted to byte row offsets (row stride 512 B)
  {
    int4 nv = *(const int4*)(nl + (size_t)(db * Pn + p0) * Kn + t * 4);
    nv.x <<= 9; nv.y <<= 9; nv.z <<= 9; nv.w <<= 9;
    *(int4*)&nlds[t * 4] = nv;
  }

  const float Ww0 = Ww[l15], Ww1 = Ww[16 + l15], Ww2 = Ww[32 + l15];
  const float bw0 = bwv[l15];

  // weight A-frags for my 8 points: A[m=w_out=l15][k=q*8+j]
  short8 af[8];
#pragma unroll
  for (int i = 0; i < 8; ++i) {
    const int p = p0 + w * 8 + i;
    const int pk = (db * Pn + p) * Kn;
    const float* __restrict__ lcp = lc + (size_t)(pk + q * 8) * 3;
    float la[24];
#pragma unroll
    for (int v = 0; v < 6; ++v) *(float4v*)&la[v * 4] = *(const float4v*)(lcp + v * 4);
#pragma unroll
    for (int j = 0; j < 8; ++j) {
      float ww = bw0 + la[3 * j] * Ww0 + la[3 * j + 1] * Ww1 + la[3 * j + 2] * Ww2;
      af[i][j] = (short)bf16b(ww);
    }
  }

  float4v acc[2][2];
#pragma unroll
  for (int pt = 0; pt < 2; ++pt)
#pragma unroll
    for (int nt = 0; nt < 2; ++nt) acc[pt][nt] = (float4v){0.f, 0.f, 0.f, 0.f};

  __syncthreads();   // nlds ready

  // my n-slice: channels w*32 .. w*32+31
  const unsigned short* __restrict__ bpt =
      WlT + (size_t)(w * 32 + l15) * 2048 + q * 8;
  const unsigned cvoff = (unsigned)(l15 * 4);

// issue 8 gathers for point (i), chunk (ct) into fdst[8]
#define ISSUE(i, ct, fdst)                                                 \
  {                                                                        \
    const int pi_ = w * 8 + (i);                                           \
    int nk_[8];                                                            \
    *(int4*)&nk_[0] = *(const int4*)&nlds[pi_ * 32 + q * 8];               \
    *(int4*)&nk_[4] = *(const int4*)&nlds[pi_ * 32 + q * 8 + 4];           \
    _Pragma("unroll") for (int j = 0; j < 8; ++j)                          \
        fdst[j] = *(const float*)(pbase + ((unsigned)nk_[j] + cvoff +      \
                                           (unsigned)((ct) * 64)));        \
  }

// pack + step1 MFMA + two-sided-swizzled ds_write for point (i)
// col = l15*32 + q*8 -> (col>>5)&7 = l15&7; XOR = ((pi&7)^(l15&7))<<4
#define FIN(i, fsrc)                                                       \
  {                                                                        \
    const int pi_ = w * 8 + (i);                                           \
    union { short8 s; unsigned u[4]; } bv_;                                \
    bv_.u[0] = pkhi(fsrc[0], fsrc[1]);                                     \
    bv_.u[1] = pkhi(fsrc[2], fsrc[3]);                                     \
    bv_.u[2] = pkhi(fsrc[4], fsrc[5]);                                     \
    bv_.u[3] = pkhi(fsrc[6], fsrc[7]);                                     \
    float4v d_ = {0.f, 0.f, 0.f, 0.f};                                     \
    d_ = __builtin_amdgcn_mfma_f32_16x16x32_bf16(af[i], bv_.s, d_, 0, 0, 0); \
    const unsigned off_ = (unsigned)(pi_ * 512 + ((l15 * 32 + q * 8) ^     \
        ((((pi_ & 7) ^ (l15 & 7)) & 7) << 4)));                            \
    uint2 u_;                                                              \
    u_.x = pkhi(d_[0], d_[1]);                                             \
    u_.y = pkhi(d_[2], d_[3]);                                             \
    *(uint2*)((char*)Mlds + off_) = u_;                                    \
  }

  float fb[4][8];   // 4-point lookahead ring (32 VGPRs, static indices)

  for (int ct = 0; ct < 8; ++ct) {
    // ---- phase B: step1 — M tiles for my 8 points, c-range [ct*16,+16)
    ISSUE(0, ct, fb[0])
    ISSUE(1, ct, fb[1])
    ISSUE(2, ct, fb[2])
    ISSUE(3, ct, fb[3])
#pragma unroll
    for (int i = 0; i < 8; ++i) {
      FIN(i, fb[i & 3])
      if (i + 4 < 8) ISSUE(i + 4, ct, fb[i & 3])
    }
    __syncthreads();
    // ---- phase A: step2 — Y += Mchunk @ WlT-chunk for my 32 channels
    // read row = l15 (point), col = ks*64+q*16; (col>>5)&7 = (ks*2+(q>>1))&7
    const unsigned short* __restrict__ bp = bpt + ct * 256;
    __builtin_amdgcn_s_setprio(1);
#pragma unroll
    for (int ks = 0; ks < 8; ++ks) {
      const unsigned ax = (unsigned)((ks * 64 + q * 16) ^
          ((((l15 & 7) ^ ((ks * 2 + (q >> 1)) & 7)) & 7) << 4));
      short8 a0 = *(const short8*)((const char*)Mlds + l15 * 512 + ax);
      short8 a1 = *(const short8*)((const char*)Mlds + (16 + l15) * 512 + ax);
      short8 b0 = *(const short8*)(bp + ks * 32);
      short8 b1 = *(const short8*)(bp + 32768 + ks * 32);
      acc[0][0] = __builtin_amdgcn_mfma_f32_16x16x32_bf16(a0, b0, acc[0][0], 0, 0, 0);
      acc[0][1] = __builtin_amdgcn_mfma_f32_16x16x32_bf16(a0, b1, acc[0][1], 0, 0, 0);
      acc[1][0] = __builtin_amdgcn_mfma_f32_16x16x32_bf16(a1, b0, acc[1][0], 0, 0, 0);
      acc[1][1] = __builtin_amdgcn_mfma_f32_16x16x32_bf16(a1, b1, acc[1][1], 0, 0, 0);
    }
    __builtin_amdgcn_s_setprio(0);
    __syncthreads();
  }
#undef ISSUE
#undef FIN

  // epilogue: bias, transposed store (B,C,P), disjoint per-wave channel stats
#pragma unroll
  for (int nt = 0; nt < 2; ++nt) {
    const int ch = w * 32 + nt * 16 + l15;
    const float bb = blv[ch];
    float s = 0.f, sq = 0.f;
#pragma unroll
    for (int pt = 0; pt < 2; ++pt) {
      float4v o;
#pragma unroll
      for (int r = 0; r < 4; ++r) {
        float v = acc[pt][nt][r] + bb; o[r] = v; s += v; sq += v * v;
      }
      *(float4v*)(xout + ((size_t)(b * Cn + ch)) * Pn + p0 + pt * 16 + q * 4) = o;
    }
    s += __shfl_xor(s, 16); s += __shfl_xor(s, 32);
    sq += __shfl_xor(sq, 16); sq += __shfl_xor(sq, 32);
    if (lane < 16) { red[ch] = s; red[128 + ch] = sq; }
  }
  __syncthreads();
  atomicAdd(&gacc[t], red[t]);
}

// ---------------------------------------------------------------------------
// finalize: layernorm (per-channel over B*P) + relu, in place on x chunk
// ---------------------------------------------------------------------------
__global__ __launch_bounds__(256) void finalize_ln(float* __restrict__ x,
                                                   const float* __restrict__ gacc,
                                                   const float* __restrict__ gamma,
                                                   const float* __restrict__ beta) {
  const int idx = blockIdx.x * 256 + threadIdx.x;
  const int fi = idx * 4;
  const int c = (fi >> 12) & 127;
  const float inv = 1.f / 32768.f;
  const float mean = gacc[c] * inv;
  const float var = gacc[128 + c] * inv - mean * mean;
  const float scale = rsqrtf(var + 1e-5f) * gamma[c];
  const float shift = beta[c] - mean * scale;
  float4v v = *(float4v*)(x + fi);
#pragma unroll
  for (int r = 0; r < 4; ++r) v[r] = fmaxf(v[r] * scale + shift, 0.f);
  *(float4v*)(x + fi) = v;
}

extern "C" void kernel_launch(void* const* d_in, const int* in_sizes, int n_in,
                              void* d_out, int out_size, void* d_ws, size_t ws_size,
                              hipStream_t stream) {
  const float* xyz    = (const float*)d_in[0];
  const float* points = (const float*)d_in[1];
  const float* lc     = (const float*)d_in[2];
  const int*   nl     = (const int*)d_in[3];
  const int*   didx   = (const int*)d_in[4];
  const float* Ww     = (const float*)d_in[5];
  const float* bw     = (const float*)d_in[6];
  const float* Wl     = (const float*)d_in[7];
  const float* bl     = (const float*)d_in[8];
  const float* gamma  = (const float*)d_in[9];
  const float* beta   = (const float*)d_in[10];

  float* out  = (float*)d_out;
  float* xout = out + (size_t)Bn * Pn * 3;                       // x chunk (B,C,P)
  unsigned short* WlT = (unsigned short*)d_ws;                   // 512 KB
  float* gacc = (float*)((char*)d_ws + (size_t)512 * 1024);      // 1 KB

  prep<<<96, 256, 0, stream>>>(Wl, WlT, xyz, out, gacc);
  fused<<<1024, 256, 0, stream>>>(points, lc, nl, didx, Ww, bw, WlT, bl,
                                  xout, gacc);
  finalize_ln<<<4096, 256, 0, stream>>>(xout, gacc, gamma, beta);
}